// Round 6
// baseline (678.762 us; speedup 1.0000x reference)
//
#include <hip/hip_runtime.h>
#include <hip/hip_bf16.h>

#define NTOK 9216   // H*W
#define CCH  256    // C
#define DQK  32     // CQ
#define BJ   64     // j-columns per attention block
#define BI   64     // i-rows per iteration
#define SSEG 4      // i-split factor (segments of 2304 rows)
#define SI   72     // Pl row stride (shorts): 144B rows, 16B aligned

typedef __attribute__((ext_vector_type(8))) short short8;
typedef __attribute__((ext_vector_type(4))) float f32x4;

__device__ __forceinline__ unsigned short f2bf(float x) {
    union { float f; unsigned int u; } v; v.f = x;
    return (unsigned short)((v.u + 0x7FFF + ((v.u >> 16) & 1)) >> 16); // RNE
}

// ---------------- Kernel 1: QKV projection (unchanged from R5) ----------------
__global__ __launch_bounds__(256) void qkv_kernel(
    const float* __restrict__ x, const float* __restrict__ w,
    unsigned short* __restrict__ qT, unsigned short* __restrict__ kT,
    unsigned short* __restrict__ vcn)
{
    const int t  = threadIdx.x;
    const int n  = blockIdx.x * 256 + t;
    const int o0 = blockIdx.y * 32;
    const int b  = blockIdx.z;
    const float* xb = x + (size_t)b * CCH * NTOK + n;
    const float* wr = w + (size_t)o0 * CCH;   // uniform address -> s_load

    float acc[32];
#pragma unroll
    for (int o = 0; o < 32; ++o) acc[o] = 0.f;

#pragma unroll 8
    for (int c = 0; c < CCH; ++c) {
        float xv = xb[(size_t)c * NTOK];
#pragma unroll
        for (int o = 0; o < 32; ++o)
            acc[o] += wr[o * CCH + c] * xv;
    }

    if (o0 < 64) {
        unsigned short* dst = ((o0 == 0) ? qT : kT) + ((size_t)b * NTOK + n) * DQK;
#pragma unroll
        for (int o = 0; o < 32; ++o) dst[o] = f2bf(acc[o]);
    } else {
        unsigned short* dst = vcn + ((size_t)b * CCH + (o0 - 64)) * NTOK + n;
#pragma unroll
        for (int o = 0; o < 32; ++o)
            dst[(size_t)o * NTOK] = f2bf(acc[o]);           // lanes coalesce along n
    }
}

// ---------------- Kernel 2: split-i flash attention partials ----------------
// Block (jt, s, b): j-tile of 64, i-segment s of NTOK/SSEG rows.
// Accumulates raw O[j][c] and l[j] for its segment, atomicAdds into Osum/lsum.
// (no max-subtraction: partials combine by plain summation)
__global__ __launch_bounds__(256, 4) void attn_partial_kernel(
    const unsigned short* __restrict__ qT, const unsigned short* __restrict__ kT,
    const unsigned short* __restrict__ vcn,
    float* __restrict__ Osum, float* __restrict__ lsum)
{
    __shared__ __align__(16) unsigned short Pl[BJ * SI]; // 9216 B

    const int t    = threadIdx.x;
    const int wv   = t >> 6;
    const int lane = t & 63;
    const int l15  = lane & 15;
    const int qd   = lane >> 4;
    const int j0   = blockIdx.x * BJ;
    const int s    = blockIdx.y;
    const int b    = blockIdx.z;
    const int iBeg = s * (NTOK / SSEG);
    const int iEnd = iBeg + (NTOK / SSEG);

    const unsigned short* qTb = qT + (size_t)b * NTOK * DQK;

    // resident k B-frags: B[k=d=qd*8+e][n=j=16jt+l15]
    short8 kf[4];
#pragma unroll
    for (int jt = 0; jt < 4; ++jt)
        kf[jt] = *(const short8*)(kT + ((size_t)b * NTOK + j0 + 16 * jt + l15) * DQK + qd * 8);

    f32x4 acc[4][4]; // O[j = j0+16mt+4qd+r][c = 64wv+16ct+l15]
#pragma unroll
    for (int mt = 0; mt < 4; ++mt)
#pragma unroll
        for (int ct = 0; ct < 4; ++ct)
            acc[mt][ct] = (f32x4){0.f, 0.f, 0.f, 0.f};
    float lw[4] = {0.f, 0.f, 0.f, 0.f}; // partial l, col j = 16jt+l15 (wave's i rows)

    const unsigned short* qrow = qTb + (size_t)(16 * wv + l15) * DQK + qd * 8;
    const unsigned short* vrow =
        vcn + (size_t)b * CCH * NTOK + (size_t)(64 * wv + l15) * NTOK + qd * 8;

    for (int i0 = iBeg; i0 < iEnd; i0 += BI) {
        // A-frag of q rows: A[m=l15 -> i=i0+16wv+l15][k=d=qd*8+e]
        short8 af = *(const short8*)(qrow + (size_t)i0 * DQK);
        // V B-frags: B[k=i_loc=32kc+qd*8+e][n=c=64wv+16ct+l15]
        short8 vf[2][4];
#pragma unroll
        for (int kc = 0; kc < 2; ++kc)
#pragma unroll
            for (int ct = 0; ct < 4; ++ct)
                vf[kc][ct] = *(const short8*)(vrow + (size_t)(16 * ct) * NTOK + i0 + 32 * kc);

        // QK: s[jt][r] = S[i = i0+16wv+4qd+r][j = j0+16jt+l15]
        f32x4 sc[4];
#pragma unroll
        for (int jt = 0; jt < 4; ++jt)
            sc[jt] = __builtin_amdgcn_mfma_f32_16x16x32_bf16(
                af, kf[jt], (f32x4){0.f, 0.f, 0.f, 0.f}, 0, 0, 0);

        // P = exp(S); fp32 partial l; write P^T to Pl[j_loc][i_loc]
#pragma unroll
        for (int jt = 0; jt < 4; ++jt) {
            float p0 = __expf(sc[jt][0]);
            float p1 = __expf(sc[jt][1]);
            float p2 = __expf(sc[jt][2]);
            float p3 = __expf(sc[jt][3]);
            lw[jt] += (p0 + p1) + (p2 + p3);
            int base = (16 * jt + l15) * SI + 16 * wv + 4 * qd; // dword aligned
            *(unsigned int*)(Pl + base)     = (unsigned)f2bf(p0) | ((unsigned)f2bf(p1) << 16);
            *(unsigned int*)(Pl + base + 2) = (unsigned)f2bf(p2) | ((unsigned)f2bf(p3) << 16);
        }
        __syncthreads(); // B1: P visible to all waves

        // PV: A = Pl rows (m=l15 -> j=16mt+l15, k=i_loc=32kc+qd*8+e), B = vf
#pragma unroll
        for (int kc = 0; kc < 2; ++kc) {
            short8 pa[4];
#pragma unroll
            for (int mt = 0; mt < 4; ++mt)
                pa[mt] = *(const short8*)(Pl + (16 * mt + l15) * SI + 32 * kc + qd * 8);
#pragma unroll
            for (int mt = 0; mt < 4; ++mt)
#pragma unroll
                for (int ct = 0; ct < 4; ++ct)
                    acc[mt][ct] = __builtin_amdgcn_mfma_f32_16x16x32_bf16(
                        pa[mt], vf[kc][ct], acc[mt][ct], 0, 0, 0);
        }
        __syncthreads(); // B2: PV reads done before next iteration's P writes
    }

    // l partial: reduce over qd (lanes 16/32 apart hold other i rows), atomicAdd
#pragma unroll
    for (int jt = 0; jt < 4; ++jt) {
        lw[jt] += __shfl_xor(lw[jt], 16);
        lw[jt] += __shfl_xor(lw[jt], 32);
    }
    if (qd == 0) {
        float* lb = lsum + (size_t)b * NTOK + j0;
#pragma unroll
        for (int jt = 0; jt < 4; ++jt)
            atomicAdd(lb + 16 * jt + l15, lw[jt]);
    }

    // O partial: direct atomic adds, Osum[b][c][j]
    float* Ob = Osum + (size_t)b * CCH * NTOK;
#pragma unroll
    for (int mt = 0; mt < 4; ++mt)
#pragma unroll
        for (int ct = 0; ct < 4; ++ct) {
            int c = 64 * wv + 16 * ct + l15;
            int j = j0 + 16 * mt + 4 * qd;
            float* p = Ob + (size_t)c * NTOK + j;
#pragma unroll
            for (int r = 0; r < 4; ++r)
                atomicAdd(p + r, acc[mt][ct][r]);
        }
}

// ---------------- Kernel 3: normalize + residual ----------------
// out[b][c][j] = gamma * Osum[b][c][j] / lsum[b][j] + x[b][c][j]
__global__ __launch_bounds__(256) void normalize_kernel(
    const float* __restrict__ Osum, const float* __restrict__ lsum,
    const float* __restrict__ x, const float* __restrict__ gamma,
    float* __restrict__ out)
{
    const size_t flat = ((size_t)blockIdx.x * 256 + threadIdx.x) * 4;
    const int j  = (int)(flat % NTOK);
    const int bc = (int)(flat / NTOK);
    const int b  = bc >> 8;
    const float g = gamma[0];

    f32x4 o = *(const f32x4*)(Osum + flat);
    f32x4 l = *(const f32x4*)(lsum + (size_t)b * NTOK + j);
    f32x4 xv = *(const f32x4*)(x + flat);
    f32x4 r;
    r[0] = g * o[0] / l[0] + xv[0];
    r[1] = g * o[1] / l[1] + xv[1];
    r[2] = g * o[2] / l[2] + xv[2];
    r[3] = g * o[3] / l[3] + xv[3];
    *(f32x4*)(out + flat) = r;
}

extern "C" void kernel_launch(void* const* d_in, const int* in_sizes, int n_in,
                              void* d_out, int out_size, void* d_ws, size_t ws_size,
                              hipStream_t stream) {
    const float* x     = (const float*)d_in[0];
    const float* w     = (const float*)d_in[1];
    const float* gamma = (const float*)d_in[2];
    float* out = (float*)d_out;

    unsigned short* qT  = (unsigned short*)d_ws;          // 2*9216*32 bf16 = 1.18 MB
    unsigned short* kT  = qT + (size_t)2 * NTOK * DQK;    // 1.18 MB
    unsigned short* vcn = kT + (size_t)2 * NTOK * DQK;    // 2*256*9216 bf16 = 9.44 MB
    float* Osum = (float*)(vcn + (size_t)2 * CCH * NTOK); // 2*256*9216 f32 = 18.87 MB
    float* lsum = Osum + (size_t)2 * CCH * NTOK;          // 2*9216 f32 = 73.7 KB

    // zero the atomic accumulation buffers (Osum + lsum contiguous)
    hipMemsetAsync(Osum, 0, ((size_t)2 * CCH * NTOK + (size_t)2 * NTOK) * sizeof(float),
                   stream);

    dim3 g1(NTOK / 256, 320 / 32, 2);
    qkv_kernel<<<g1, 256, 0, stream>>>(x, w, qT, kT, vcn);

    dim3 g2(NTOK / BJ, SSEG, 2);
    attn_partial_kernel<<<g2, 256, 0, stream>>>(qT, kT, vcn, Osum, lsum);

    dim3 g3((unsigned)((size_t)2 * CCH * NTOK / 4 / 256));
    normalize_kernel<<<g3, 256, 0, stream>>>(Osum, lsum, x, gamma, out);
}

// Round 7
// 416.346 us; speedup vs baseline: 1.6303x; 1.6303x over previous
//
#include <hip/hip_runtime.h>
#include <hip/hip_bf16.h>

#define NTOK 9216   // H*W
#define CCH  256    // C
#define DQK  32     // CQ
#define BJ   128    // j-columns per attention block
#define BI   64     // i-rows per iteration
#define SSEG 4      // i-split factor (segments of 2304 rows)
#define SI   72     // Pl row stride (shorts): 144B rows, 16B aligned

typedef __attribute__((ext_vector_type(8))) short short8;
typedef __attribute__((ext_vector_type(4))) float f32x4;

__device__ __forceinline__ unsigned short f2bf(float x) {
    union { float f; unsigned int u; } v; v.f = x;
    return (unsigned short)((v.u + 0x7FFF + ((v.u >> 16) & 1)) >> 16); // RNE
}

// ---------------- Kernel 1: QKV projection (XCD-swizzled) ----------------
// 720 logical blocks = 72 (n-swath,batch) x 10 o-tiles. Swizzle so each XCD
// owns 9 n-swaths (x-slice 2.3 MB -> L2-resident across its 10 o-passes).
__global__ __launch_bounds__(256) void qkv_kernel(
    const float* __restrict__ x, const float* __restrict__ w,
    unsigned short* __restrict__ qT, unsigned short* __restrict__ kT,
    unsigned short* __restrict__ vcn)
{
    const int id  = blockIdx.x;
    const int xcd = id & 7;
    const int sq  = id >> 3;            // 0..89
    const int nsb = xcd * 9 + sq / 10;  // 0..71  (n-swath, batch) pair
    const int o0  = (sq % 10) * 32;
    const int b   = nsb / 36;
    const int n   = (nsb % 36) * 256 + threadIdx.x;

    const float* xb = x + (size_t)b * CCH * NTOK + n;
    const float* wr = w + (size_t)o0 * CCH;   // uniform address -> s_load

    float acc[32];
#pragma unroll
    for (int o = 0; o < 32; ++o) acc[o] = 0.f;

#pragma unroll 8
    for (int c = 0; c < CCH; ++c) {
        float xv = xb[(size_t)c * NTOK];
#pragma unroll
        for (int o = 0; o < 32; ++o)
            acc[o] += wr[o * CCH + c] * xv;
    }

    if (o0 < 64) {
        unsigned short* dst = ((o0 == 0) ? qT : kT) + ((size_t)b * NTOK + n) * DQK;
#pragma unroll
        for (int o = 0; o < 32; ++o) dst[o] = f2bf(acc[o]);
    } else {
        unsigned short* dst = vcn + ((size_t)b * CCH + (o0 - 64)) * NTOK + n;
#pragma unroll
        for (int o = 0; o < 32; ++o)
            dst[(size_t)o * NTOK] = f2bf(acc[o]);           // lanes coalesce along n
    }
}

// ---------------- Kernel 2: split-i flash attention partials ----------------
// 1152 blocks = 8 XCD-combos (seg 0..3 x c-half 0..1) x 144 (j-block 0..71 x b).
// Each XCD streams ONE V chunk (2304 i x 128 c x 2 batches = 1.18 MB, L2-resident).
// Block: 128 j x 128 c tile; wave (jh,u): QK i-half u / PV c-quarter u.
// Plain stores of raw partial O and l (no atomics; combined by reduce_kernel).
__global__ __launch_bounds__(256, 3) void attn_partial_kernel(
    const unsigned short* __restrict__ qT, const unsigned short* __restrict__ kT,
    const unsigned short* __restrict__ vcn,
    float* __restrict__ Opart, float* __restrict__ lpart)
{
    __shared__ __align__(16) unsigned short Pl[BJ * SI]; // 18432 B
    __shared__ float lred2[2 * BJ];                      // 1024 B

    const int id  = blockIdx.x;
    const int xcd = id & 7;
    const int s   = xcd >> 1;          // i-segment 0..3
    const int cb  = xcd & 1;           // c-half 0..1
    const int r   = id >> 3;           // 0..143
    const int jb  = r % 72;
    const int b   = r / 72;

    const int t    = threadIdx.x;
    const int wv   = t >> 6;
    const int lane = t & 63;
    const int l15  = lane & 15;
    const int qd   = lane >> 4;
    const int jh   = wv >> 1;          // j-half within block
    const int u    = wv & 1;           // QK: i-subtile bit; PV: c-quarter bit
    const int j0   = jb * BJ;
    const int c0   = cb * 128;
    const int iBeg = s * (NTOK / SSEG);
    const int iEnd = iBeg + (NTOK / SSEG);

    // resident k B-frags: B[k=d=qd*8+e][n=j=64jh+16jt+l15]
    short8 kf[4];
#pragma unroll
    for (int jt = 0; jt < 4; ++jt)
        kf[jt] = *(const short8*)(kT +
            ((size_t)b * NTOK + j0 + 64 * jh + 16 * jt + l15) * DQK + qd * 8);

    f32x4 acc[4][4]; // O[j = j0+64jh+16mt+4qd+r][c = c0+64u+16ct+l15]
#pragma unroll
    for (int mt = 0; mt < 4; ++mt)
#pragma unroll
        for (int ct = 0; ct < 4; ++ct)
            acc[mt][ct] = (f32x4){0.f, 0.f, 0.f, 0.f};
    float lw[4] = {0.f, 0.f, 0.f, 0.f}; // partial l, col j = 64jh+16jt+l15

    const unsigned short* qrow =
        qT + (size_t)b * NTOK * DQK + (size_t)(16 * u + l15) * DQK + qd * 8;
    const unsigned short* vrow =
        vcn + ((size_t)b * CCH + c0 + 64 * u + l15) * NTOK + qd * 8;

    for (int i0 = iBeg; i0 < iEnd; i0 += BI) {
        // A-frags of q rows: af[it] -> i = i0 + 32it + 16u + l15
        short8 af[2];
#pragma unroll
        for (int it = 0; it < 2; ++it)
            af[it] = *(const short8*)(qrow + (size_t)(i0 + 32 * it) * DQK);
        // V B-frags: B[k=i_loc=32kc+qd*8+e][n=c=c0+64u+16ct+l15]
        short8 vf[2][4];
#pragma unroll
        for (int kc = 0; kc < 2; ++kc)
#pragma unroll
            for (int ct = 0; ct < 4; ++ct)
                vf[kc][ct] = *(const short8*)(vrow + (size_t)(16 * ct) * NTOK + i0 + 32 * kc);

        // QK: S[i = i0+32it+16u+4qd+rr][j = j0+64jh+16jt+l15]
#pragma unroll
        for (int it = 0; it < 2; ++it) {
#pragma unroll
            for (int jt = 0; jt < 4; ++jt) {
                f32x4 sc = __builtin_amdgcn_mfma_f32_16x16x32_bf16(
                    af[it], kf[jt], (f32x4){0.f, 0.f, 0.f, 0.f}, 0, 0, 0);
                float p0 = __expf(sc[0]);
                float p1 = __expf(sc[1]);
                float p2 = __expf(sc[2]);
                float p3 = __expf(sc[3]);
                lw[jt] += (p0 + p1) + (p2 + p3);
                // Pl[j_loc][i_loc], i_loc = 32it+16u+4qd+{0..3} (dword aligned)
                int base = (64 * jh + 16 * jt + l15) * SI + 32 * it + 16 * u + 4 * qd;
                *(unsigned int*)(Pl + base)     = (unsigned)f2bf(p0) | ((unsigned)f2bf(p1) << 16);
                *(unsigned int*)(Pl + base + 2) = (unsigned)f2bf(p2) | ((unsigned)f2bf(p3) << 16);
            }
        }
        __syncthreads(); // B1: P visible to all waves

        // PV: A = Pl rows (m=l15 -> j=64jh+16mt+l15, k=32kc+qd*8+e), B = vf
#pragma unroll
        for (int kc = 0; kc < 2; ++kc) {
            short8 pa[4];
#pragma unroll
            for (int mt = 0; mt < 4; ++mt)
                pa[mt] = *(const short8*)(Pl + (64 * jh + 16 * mt + l15) * SI + 32 * kc + qd * 8);
#pragma unroll
            for (int mt = 0; mt < 4; ++mt)
#pragma unroll
                for (int ct = 0; ct < 4; ++ct)
                    acc[mt][ct] = __builtin_amdgcn_mfma_f32_16x16x32_bf16(
                        pa[mt], vf[kc][ct], acc[mt][ct], 0, 0, 0);
        }
        __syncthreads(); // B2: PV reads done before next iteration's P writes
    }

    // l partial: sum over qd (this wave covered i-subsets 32it+16u+[0,16))
#pragma unroll
    for (int jt = 0; jt < 4; ++jt) {
        lw[jt] += __shfl_xor(lw[jt], 16);
        lw[jt] += __shfl_xor(lw[jt], 32);
    }
    if (qd == 0) {
#pragma unroll
        for (int jt = 0; jt < 4; ++jt)
            lred2[u * BJ + 64 * jh + 16 * jt + l15] = lw[jt];
    }
    __syncthreads();
    if (cb == 0 && t < BJ)   // c-half 1 computes identical l; write once
        lpart[(size_t)(s * 2 + b) * NTOK + j0 + t] = lred2[t] + lred2[BJ + t];

    // store raw partial O (plain, disjoint, coalesced f32x4 along j)
#pragma unroll
    for (int mt = 0; mt < 4; ++mt)
#pragma unroll
        for (int ct = 0; ct < 4; ++ct) {
            int c = c0 + 64 * u + 16 * ct + l15;
            int j = j0 + 64 * jh + 16 * mt + 4 * qd;
            float* p = Opart + ((size_t)(s * 2 + b) * CCH + c) * NTOK + j;
            *(f32x4*)p = acc[mt][ct];
        }
}

// ---------------- Kernel 3: reduce partials + normalize + residual ----------------
// out[b][c][j] = gamma * (sum_s Opart[s][b][c][j]) / (sum_s lpart[s][b][j]) + x
__global__ __launch_bounds__(256) void reduce_kernel(
    const float* __restrict__ Opart, const float* __restrict__ lpart,
    const float* __restrict__ x, const float* __restrict__ gamma,
    float* __restrict__ out)
{
    const size_t flat = ((size_t)blockIdx.x * 256 + threadIdx.x) * 4;
    const int j = (int)(flat % NTOK);
    const int b = (int)(flat / ((size_t)CCH * NTOK));
    const size_t inb = flat - (size_t)b * CCH * NTOK;  // c*NTOK + j

    f32x4 o = {0.f, 0.f, 0.f, 0.f};
    f32x4 l = {0.f, 0.f, 0.f, 0.f};
#pragma unroll
    for (int s = 0; s < SSEG; ++s) {
        const size_t plane = (size_t)(s * 2 + b) * CCH * NTOK;
        f32x4 ov = *(const f32x4*)(Opart + plane + inb);
        f32x4 lv = *(const f32x4*)(lpart + (size_t)(s * 2 + b) * NTOK + j);
        o[0] += ov[0]; o[1] += ov[1]; o[2] += ov[2]; o[3] += ov[3];
        l[0] += lv[0]; l[1] += lv[1]; l[2] += lv[2]; l[3] += lv[3];
    }
    const float g = gamma[0];
    f32x4 xv = *(const f32x4*)(x + flat);
    f32x4 rr;
    rr[0] = g * o[0] / l[0] + xv[0];
    rr[1] = g * o[1] / l[1] + xv[1];
    rr[2] = g * o[2] / l[2] + xv[2];
    rr[3] = g * o[3] / l[3] + xv[3];
    *(f32x4*)(out + flat) = rr;
}

extern "C" void kernel_launch(void* const* d_in, const int* in_sizes, int n_in,
                              void* d_out, int out_size, void* d_ws, size_t ws_size,
                              hipStream_t stream) {
    const float* x     = (const float*)d_in[0];
    const float* w     = (const float*)d_in[1];
    const float* gamma = (const float*)d_in[2];
    float* out = (float*)d_out;

    unsigned short* qT  = (unsigned short*)d_ws;          // 1.18 MB
    unsigned short* kT  = qT + (size_t)2 * NTOK * DQK;    // 1.18 MB
    unsigned short* vcn = kT + (size_t)2 * NTOK * DQK;    // 9.44 MB
    float* Opart = (float*)(vcn + (size_t)2 * CCH * NTOK); // 4*2*256*9216 f32 = 75.5 MB
    float* lpart = Opart + (size_t)SSEG * 2 * CCH * NTOK;  // 4*2*9216 f32 = 295 KB
    // total ws use: 87.6 MB (fully overwritten each call -> no memset needed)

    qkv_kernel<<<720, 256, 0, stream>>>(x, w, qT, kT, vcn);

    attn_partial_kernel<<<1152, 256, 0, stream>>>(qT, kT, vcn, Opart, lpart);

    reduce_kernel<<<(unsigned)((size_t)2 * CCH * NTOK / 4 / 256), 256, 0, stream>>>(
        Opart, lpart, x, gamma, out);
}